// Round 12
// baseline (166.291 us; speedup 1.0000x reference)
//
#include <hip/hip_runtime.h>
#include <hip/hip_bf16.h>

// Problem constants (B=4096, D=1024 per reference setup_inputs)
#define B_ROWS 4096
#define D_DIM  1024          // elements == bytes in fp8
#define N_ROWS 8192          // 2B
// values scaled by 16 before fp8 cast -> sim scaled by 256; exp arg factor:
#define EXP_SCALE 0.0078125f // TEMP_INV / 256 = 2/256
#define FP8_SCALE 16.0f

#define NTILE 64
#define GRID_SIM 2080        // upper-triangle tiles incl. diagonal (8 x 260)

typedef __attribute__((ext_vector_type(4))) float f32x4;   // MFMA C/D frag
typedef __attribute__((ext_vector_type(8))) int   i32x8;   // MX MFMA A/B frag

// Async global->LDS DMA, 16 B per lane. LDS dest is WAVE-UNIFORM base;
// lane i's 16 B land at base + i*16 (per-lane global addr is free-form).
__device__ inline void load_lds16(const unsigned char* g, unsigned char* l) {
    __builtin_amdgcn_global_load_lds(
        (const __attribute__((address_space(1))) unsigned int*)g,
        (__attribute__((address_space(3))) unsigned int*)l,
        16, 0, 0);
}

// ---------------------------------------------------------------------------
// Kernel 1 (R13 form, proven): block-per-row L2 normalize -> fp8 e4m3 reps
// (x16 scale), [8192] rows x 1024 B. 4096 blocks x 256 thr; thread t owns
// elements 4t..4t+3 of row b in BOTH emb_i and emb_j. Coalesced 16 B/lane
// loads, butterfly + LDS cross-wave reduce, 4 B/lane fp8 stores.
// pos[b] = z_i(b).z_j(b) in fp32 (exact). Zeroes denom (blocks 0..31).
// ---------------------------------------------------------------------------
__global__ __launch_bounds__(256)
void normalize_kernel(const float* __restrict__ emb_i,
                      const float* __restrict__ emb_j,
                      unsigned char* __restrict__ reps,
                      float* __restrict__ pos,
                      float* __restrict__ denom) {
    const int b    = blockIdx.x;                     // 0..4095 (one row pair)
    const int t    = threadIdx.x;                    // 0..255
    const int lane = t & 63;
    const int wave = t >> 6;

    if (b < N_ROWS / 256) denom[b * 256 + t] = 0.0f;

    const float4 vi = ((const float4*)(emb_i + (size_t)b * D_DIM))[t];
    const float4 vj = ((const float4*)(emb_j + (size_t)b * D_DIM))[t];

    float si = vi.x*vi.x + vi.y*vi.y + vi.z*vi.z + vi.w*vi.w;
    float sj = vj.x*vj.x + vj.y*vj.y + vj.z*vj.z + vj.w*vj.w;
    float sd = vi.x*vj.x + vi.y*vj.y + vi.z*vj.z + vi.w*vj.w;

    #pragma unroll
    for (int off = 32; off >= 1; off >>= 1) {   // butterfly within wave
        si += __shfl_xor(si, off);
        sj += __shfl_xor(sj, off);
        sd += __shfl_xor(sd, off);
    }
    __shared__ float red[3][4];
    if (lane == 0) { red[0][wave] = si; red[1][wave] = sj; red[2][wave] = sd; }
    __syncthreads();
    si = red[0][0] + red[0][1] + red[0][2] + red[0][3];
    sj = red[1][0] + red[1][1] + red[1][2] + red[1][3];
    sd = red[2][0] + red[2][1] + red[2][2] + red[2][3];

    const float inv_i = FP8_SCALE / fmaxf(sqrtf(si), 1e-12f);
    const float inv_j = FP8_SCALE / fmaxf(sqrtf(sj), 1e-12f);
    if (t == 0) pos[b] = sd * (inv_i * inv_j) * (1.0f / (FP8_SCALE * FP8_SCALE));

    int a  = __builtin_amdgcn_cvt_pk_fp8_f32(vi.x * inv_i, vi.y * inv_i, 0, false);
    unsigned int ui = __builtin_amdgcn_cvt_pk_fp8_f32(vi.z * inv_i, vi.w * inv_i, a, true);
    int c  = __builtin_amdgcn_cvt_pk_fp8_f32(vj.x * inv_j, vj.y * inv_j, 0, false);
    unsigned int uj = __builtin_amdgcn_cvt_pk_fp8_f32(vj.z * inv_j, vj.w * inv_j, c, true);

    ((unsigned int*)(reps + (size_t)b * D_DIM))[t]            = ui;
    ((unsigned int*)(reps + (size_t)(b + B_ROWS) * D_DIM))[t] = uj;
}

// ---------------------------------------------------------------------------
// Kernel 2 (R20): R19 + B-PANEL FROM GLOBAL (no B LDS staging).
//
// WHY (m169 class: don't stage what L2 fits): the B path had 2x LDS read
// amplification (each wave reads 8 KB of B staged once) and half the
// gload_lds drain depth. The XOR swizzle is purely SPATIAL: LDS slot
// (2q)^(r&7) holds global chunk (2q)^(r&7)^(r&7) = 2q — lanes read their
// TRUE k-chunk. So B can be loaded straight from global at
// row*1024 + kb + quad*32 (+16) with identical fragment semantics.
// Effects: LDS 32->16 KB, ds_reads/iter 16->8 per wave, DMA calls 8->4
// (drain half), structural write-conflict cycles halved. B loads are
// issued at the TOP of the iter so L2 latency hides under the barrier +
// A staging; counted vmcnt lets MFMAs wait only on B arrivals.
//
// Keeps: XCD swizzle (R18, FETCH 77->33 MB), R19 ordering for A
// (read frags -> barrier -> stage next -> MFMA -> barrier), (256,3).
// RETIRED: deeper pipelines (R9-R12), 4 blocks/CU (R14 spill), loss
// fusion any form (R15/R17). Tripwire: VGPR>~120 or WRITE balloon ->
// spill -> revert to R19.
//
// LDS (A only): 128-B rows; 16-B chunk c of row r at slot c ^ (r&7).
// Fragment reads: two ds_read_b128 at off, off^16. C/D layout is
// shape-determined (col=lane&15, row=quad*4+reg).
// ---------------------------------------------------------------------------
#define BM 128
#define BKB 128              // K-bytes (== elements) staged per iter

__global__ __launch_bounds__(256, 3)
void sim_denom_kernel(const unsigned char* __restrict__ reps,
                      float* __restrict__ denom) {
    // ---- XCD-aware swizzle: physical bid -> logical tile id (R18) ----
    const int bid = (blockIdx.x & 7) * (GRID_SIM / 8) + (blockIdx.x >> 3);

    // ---- tile decode: bid -> (rt, ct), rt <= ct (grouped enumeration) ----
    int g = (int)((__builtin_sqrtf(1.0f + 8.0f * (float)bid) - 1.0f) * 0.125f);
    while (8 * (g + 1) * (g + 1) + 2 * (g + 1) <= bid) g++;
    while (8 * g * g + 2 * g > bid) g--;
    const int i = bid - (8 * g * g + 2 * g);    // [0, 16g+10)
    int rt, c;
    if (i < 16 * g + 4) { rt = i >> 2; c = i & 3; }
    else {
        const int r2 = i - (16 * g + 4);        // 0..5
        const int ra[6] = {1, 1, 1, 2, 2, 3};
        const int ca[6] = {1, 2, 3, 2, 3, 3};
        rt = 4 * g + ra[r2]; c = ca[r2];
    }
    const int ct = 4 * g + c;
    const bool isDiag = (rt == ct);
    const int rowBase = rt * BM;
    const int colBase = ct * BM;

    const int t    = threadIdx.x;
    const int lane = t & 63;
    const int wave = t >> 6;
    const int wr   = wave >> 1;           // wave row quadrant (0/1)
    const int wc   = wave & 1;            // wave col quadrant (0/1)
    const int quad = lane >> 4;           // 0..3
    const int l15  = lane & 15;

    __shared__ __align__(16) unsigned char Asmem[BM * BKB];   // 16 KB (A only)

    // A staging lane map (unchanged): per call a wave stages 8 rows (1 KB).
    // lane i -> row (i>>3), LDS slot i&7; global chunk (i&7)^((i>>3)&7) so
    // stored slot == chunk ^ (row&7).
    const int grow = lane >> 3;                              // 0..7
    const int gcol = ((lane & 7) ^ grow) * 16;               // swizzled chunk
    const unsigned char* gA = reps + (size_t)(rowBase + wave * 8 + grow) * D_DIM + gcol;
    unsigned char* lA = Asmem + wave * 8 * BKB;              // call j adds j*32*BKB

    // A fragment read offsets: row ra = wr*64 + m*16 + l15; lane reads true
    // chunks {2q, 2q+1} at slots chunk^(ra&7) -> off and off^16.
    int aoff[4];
    #pragma unroll
    for (int m = 0; m < 4; m++) {
        const int ra = wr * 64 + m * 16 + l15;
        aoff[m] = ra * BKB + ((2 * quad) ^ (ra & 7)) * 16;
    }
    // B direct-from-global base: lane's row = wc*64 + m*16 + l15, true chunk
    // 2q at byte quad*32 (+16 for the second half).
    const unsigned char* gB0 =
        reps + (size_t)(colBase + wc * 64 + l15) * D_DIM + quad * 32;

    f32x4 acc[4][4];
    #pragma unroll
    for (int mi = 0; mi < 4; mi++)
        #pragma unroll
        for (int ni = 0; ni < 4; ni++)
            acc[mi][ni] = (f32x4){0.f, 0.f, 0.f, 0.f};

    // ---- prologue: stage A tile 0, publish ----
    #pragma unroll
    for (int j = 0; j < 4; j++)
        load_lds16(gA + j * 32 * D_DIM, lA + j * 32 * BKB);
    __syncthreads();   // vmcnt(0) drain: A tile 0 published

    for (int it = 0; it < D_DIM / BKB; ++it) {   // 8 iters
        const int kb = it * BKB;

        // issue B global loads FIRST (L2 latency hides under barrier + A path)
        i32x8 bf[4];
        #pragma unroll
        for (int m = 0; m < 4; m++) {
            const int4 blo = *(const int4*)(gB0 + (size_t)m * 16 * D_DIM + kb);
            const int4 bhi = *(const int4*)(gB0 + (size_t)m * 16 * D_DIM + kb + 16);
            bf[m] = (i32x8){blo.x, blo.y, blo.z, blo.w, bhi.x, bhi.y, bhi.z, bhi.w};
        }

        // read this tile's A fragments (LDS dead after)
        i32x8 af[4];
        #pragma unroll
        for (int m = 0; m < 4; m++) {
            const int4 alo = *(const int4*)(Asmem + aoff[m]);
            const int4 ahi = *(const int4*)(Asmem + (aoff[m] ^ 16));
            af[m] = (i32x8){alo.x, alo.y, alo.z, alo.w, ahi.x, ahi.y, ahi.z, ahi.w};
        }
        __syncthreads();   // all waves done reading -> LDS overwrite safe

        // stage next A tile before the MFMAs (DMA flies under them)
        if (it < D_DIM / BKB - 1) {
            const int kn = kb + BKB;
            #pragma unroll
            for (int j = 0; j < 4; j++)
                load_lds16(gA + kn + j * 32 * D_DIM, lA + j * 32 * BKB);
        }

        #pragma unroll
        for (int mi = 0; mi < 4; mi++)
            #pragma unroll
            for (int ni = 0; ni < 4; ni++)
                acc[mi][ni] = __builtin_amdgcn_mfma_scale_f32_16x16x128_f8f6f4(
                    af[mi], bf[ni], acc[mi][ni],
                    0, 0,          // cbsz=0 (fp8 e4m3 A), blgp=0 (fp8 e4m3 B)
                    0, 127,        // scale A: opsel 0, e8m0 127 = 1.0
                    0, 127);       // scale B: unit

        if (it < D_DIM / BKB - 1) __syncthreads();   // publish (drain overlapped)
    }

    // Epilogue. C layout: col = lane&15, row = quad*4 + reg (shape-determined).
    // sim computed on 16x-scaled fp8 -> exp factor 2/256.
    float csum[4] = {0.f, 0.f, 0.f, 0.f};
    #pragma unroll
    for (int mi = 0; mi < 4; mi++) {
        const int rowA = rowBase + wr * 64 + mi * 16 + quad * 4;
        float prow[4] = {0.f, 0.f, 0.f, 0.f};
        #pragma unroll
        for (int ni = 0; ni < 4; ni++) {
            const int col = colBase + wc * 64 + ni * 16 + l15;
            const f32x4 a = acc[mi][ni];
            #pragma unroll
            for (int r = 0; r < 4; r++) {
                float e = __expf(a[r] * EXP_SCALE);
                if (isDiag && rowA + r == col) e = 0.0f;   // self-sim mask
                csum[ni] += e;
                prow[r]  += e;
            }
        }
        if (!isDiag) {
            #pragma unroll
            for (int r = 0; r < 4; r++) {   // row sums -> mirror tile
                float v = prow[r];
                v += __shfl_xor(v, 1);
                v += __shfl_xor(v, 2);
                v += __shfl_xor(v, 4);
                v += __shfl_xor(v, 8);
                if (l15 == 0) atomicAdd(denom + rowA + r, v);
            }
        }
    }
    #pragma unroll
    for (int ni = 0; ni < 4; ni++) {        // column sums across 4 quads
        float v = csum[ni];
        v += __shfl_xor(v, 16);
        v += __shfl_xor(v, 32);
        if (quad == 0)
            atomicAdd(denom + colBase + wc * 64 + ni * 16 + l15, v);
    }
}

// ---------------------------------------------------------------------------
// Kernel 3: loss = mean over 2B rows of (log(denom) - pos/T). Single block,
// 1024 threads (8 loop iters).
// ---------------------------------------------------------------------------
__global__ __launch_bounds__(1024)
void loss_kernel(const float* __restrict__ denom,
                 const float* __restrict__ pos,
                 float* __restrict__ out) {
    const int t = threadIdx.x;
    float s = 0.f;
    for (int i = t; i < N_ROWS; i += 1024) {
        const float p = pos[i & (B_ROWS - 1)];
        s += logf(denom[i]) - p * 2.0f;     // TEMP_INV, pos is unscaled fp32
    }
    #pragma unroll
    for (int off = 32; off >= 1; off >>= 1) s += __shfl_xor(s, off);
    __shared__ float red[16];
    if ((t & 63) == 0) red[t >> 6] = s;
    __syncthreads();
    if (t == 0) {
        float tot = 0.f;
        #pragma unroll
        for (int w = 0; w < 16; w++) tot += red[w];
        out[0] = tot / (float)N_ROWS;
    }
}

// ---------------------------------------------------------------------------
extern "C" void kernel_launch(void* const* d_in, const int* in_sizes, int n_in,
                              void* d_out, int out_size, void* d_ws, size_t ws_size,
                              hipStream_t stream) {
    const float* emb_i = (const float*)d_in[0];
    const float* emb_j = (const float*)d_in[1];

    unsigned char* reps = (unsigned char*)d_ws;                       // 8 MB fp8 [8192][1024]
    float* pos   = (float*)((char*)d_ws + (size_t)N_ROWS * D_DIM);    // 16 KB
    float* denom = pos + B_ROWS;                                      // 32 KB
    float* out   = (float*)d_out;

    normalize_kernel<<<B_ROWS, 256, 0, stream>>>(emb_i, emb_j, reps, pos, denom);
    sim_denom_kernel<<<GRID_SIM, 256, 0, stream>>>(reps, denom);
    loss_kernel<<<1, 1024, 0, stream>>>(denom, pos, out);
}

// Round 13
// 132.298 us; speedup vs baseline: 1.2569x; 1.2569x over previous
//
#include <hip/hip_runtime.h>
#include <hip/hip_bf16.h>

// Problem constants (B=4096, D=1024 per reference setup_inputs)
#define B_ROWS 4096
#define D_DIM  1024          // elements == bytes in fp8
#define N_ROWS 8192          // 2B
// values scaled by 16 before fp8 cast -> sim scaled by 256; exp arg factor:
#define EXP_SCALE 0.0078125f // TEMP_INV / 256 = 2/256
#define FP8_SCALE 16.0f

#define NTILE 64
#define GRID_SIM 2080        // upper-triangle tiles incl. diagonal (8 x 260)

typedef __attribute__((ext_vector_type(4))) float f32x4;   // MFMA C/D frag
typedef __attribute__((ext_vector_type(8))) int   i32x8;   // MX MFMA A/B frag

// Async global->LDS DMA, 16 B per lane. LDS dest is WAVE-UNIFORM base;
// lane i's 16 B land at base + i*16 (per-lane global addr is free-form).
__device__ inline void load_lds16(const unsigned char* g, unsigned char* l) {
    __builtin_amdgcn_global_load_lds(
        (const __attribute__((address_space(1))) unsigned int*)g,
        (__attribute__((address_space(3))) unsigned int*)l,
        16, 0, 0);
}

// ---------------------------------------------------------------------------
// Kernel 1 (R13 form, proven): block-per-row L2 normalize -> fp8 e4m3 reps
// (x16 scale), [8192] rows x 1024 B. 4096 blocks x 256 thr; thread t owns
// elements 4t..4t+3 of row b in BOTH emb_i and emb_j. Coalesced 16 B/lane
// loads, butterfly + LDS cross-wave reduce, 4 B/lane fp8 stores.
// pos[b] = z_i(b).z_j(b) in fp32 (exact). Zeroes denom (blocks 0..31).
// ---------------------------------------------------------------------------
__global__ __launch_bounds__(256)
void normalize_kernel(const float* __restrict__ emb_i,
                      const float* __restrict__ emb_j,
                      unsigned char* __restrict__ reps,
                      float* __restrict__ pos,
                      float* __restrict__ denom) {
    const int b    = blockIdx.x;                     // 0..4095 (one row pair)
    const int t    = threadIdx.x;                    // 0..255
    const int lane = t & 63;
    const int wave = t >> 6;

    if (b < N_ROWS / 256) denom[b * 256 + t] = 0.0f;

    const float4 vi = ((const float4*)(emb_i + (size_t)b * D_DIM))[t];
    const float4 vj = ((const float4*)(emb_j + (size_t)b * D_DIM))[t];

    float si = vi.x*vi.x + vi.y*vi.y + vi.z*vi.z + vi.w*vi.w;
    float sj = vj.x*vj.x + vj.y*vj.y + vj.z*vj.z + vj.w*vj.w;
    float sd = vi.x*vj.x + vi.y*vj.y + vi.z*vj.z + vi.w*vj.w;

    #pragma unroll
    for (int off = 32; off >= 1; off >>= 1) {   // butterfly within wave
        si += __shfl_xor(si, off);
        sj += __shfl_xor(sj, off);
        sd += __shfl_xor(sd, off);
    }
    __shared__ float red[3][4];
    if (lane == 0) { red[0][wave] = si; red[1][wave] = sj; red[2][wave] = sd; }
    __syncthreads();
    si = red[0][0] + red[0][1] + red[0][2] + red[0][3];
    sj = red[1][0] + red[1][1] + red[1][2] + red[1][3];
    sd = red[2][0] + red[2][1] + red[2][2] + red[2][3];

    const float inv_i = FP8_SCALE / fmaxf(sqrtf(si), 1e-12f);
    const float inv_j = FP8_SCALE / fmaxf(sqrtf(sj), 1e-12f);
    if (t == 0) pos[b] = sd * (inv_i * inv_j) * (1.0f / (FP8_SCALE * FP8_SCALE));

    int a  = __builtin_amdgcn_cvt_pk_fp8_f32(vi.x * inv_i, vi.y * inv_i, 0, false);
    unsigned int ui = __builtin_amdgcn_cvt_pk_fp8_f32(vi.z * inv_i, vi.w * inv_i, a, true);
    int c  = __builtin_amdgcn_cvt_pk_fp8_f32(vj.x * inv_j, vj.y * inv_j, 0, false);
    unsigned int uj = __builtin_amdgcn_cvt_pk_fp8_f32(vj.z * inv_j, vj.w * inv_j, c, true);

    ((unsigned int*)(reps + (size_t)b * D_DIM))[t]            = ui;
    ((unsigned int*)(reps + (size_t)(b + B_ROWS) * D_DIM))[t] = uj;
}

// ---------------------------------------------------------------------------
// Kernel 2 (R21): R19 + A-ONLY DOUBLE BUFFER (48 KB LDS, keeps 3 blocks/CU).
//
// R20 lesson (retired): direct-global B operand reads expose L2 latency
// serially in every iter (53->94 us). global_load_lds + LDS IS the
// latency-hiding; don't elide staging.
//
// This change: Asmem[2][16KB] + Bsmem[16KB] = 48 KB -> 160/48 = 3 blocks/CU
// (the invariant whose violation killed R9's 64 KB full dbuf). A's 4 DMA
// calls issue at the TOP of the iter into the idle A-buffer (safe: that
// buffer's reads finished before the previous iter's end barrier), ~250 cyc
// earlier than R19. B stays single-buffered: staged after the mid barrier
// (overwrite-safe), covered by the ~550 cyc MFMA block as in R19.
//
// Keeps: XCD swizzle (R18), read->barrier->stage->MFMA->barrier ordering
// (R19), (256,3), all verified layouts. RETIRED: deeper/full dbuf pipelines
// (R9-R12), 4 blocks/CU (R14), loss fusion (R15/R17), global operands (R20).
//
// LDS: 128-B rows; 16-B chunk c of row r at slot c ^ (r&7). Fragment
// reads: per frag two ds_read_b128 at off, off^16. A and B use the same
// lane->k map, so the k-permutation cancels in the dot product; C/D layout
// is shape-determined (col=lane&15, row=quad*4+reg).
// ---------------------------------------------------------------------------
#define BM 128
#define BKB 128              // K-bytes (== elements) staged per iter
#define KITERS (D_DIM / BKB) // 8

__global__ __launch_bounds__(256, 3)
void sim_denom_kernel(const unsigned char* __restrict__ reps,
                      float* __restrict__ denom) {
    // ---- XCD-aware swizzle: physical bid -> logical tile id (R18) ----
    const int bid = (blockIdx.x & 7) * (GRID_SIM / 8) + (blockIdx.x >> 3);

    // ---- tile decode: bid -> (rt, ct), rt <= ct (grouped enumeration) ----
    int g = (int)((__builtin_sqrtf(1.0f + 8.0f * (float)bid) - 1.0f) * 0.125f);
    while (8 * (g + 1) * (g + 1) + 2 * (g + 1) <= bid) g++;
    while (8 * g * g + 2 * g > bid) g--;
    const int i = bid - (8 * g * g + 2 * g);    // [0, 16g+10)
    int rt, c;
    if (i < 16 * g + 4) { rt = i >> 2; c = i & 3; }
    else {
        const int r2 = i - (16 * g + 4);        // 0..5
        const int ra[6] = {1, 1, 1, 2, 2, 3};
        const int ca[6] = {1, 2, 3, 2, 3, 3};
        rt = 4 * g + ra[r2]; c = ca[r2];
    }
    const int ct = 4 * g + c;
    const bool isDiag = (rt == ct);
    const int rowBase = rt * BM;
    const int colBase = ct * BM;

    const int t    = threadIdx.x;
    const int lane = t & 63;
    const int wave = t >> 6;
    const int wr   = wave >> 1;           // wave row quadrant (0/1)
    const int wc   = wave & 1;            // wave col quadrant (0/1)
    const int quad = lane >> 4;           // 0..3
    const int l15  = lane & 15;

    __shared__ __align__(16) unsigned char Asmem[2][BM * BKB];   // 2 x 16 KB
    __shared__ __align__(16) unsigned char Bsmem[BM * BKB];      // 16 KB

    // staging lane map: per call a wave stages 8 rows (1 KB). lane i ->
    // row (i>>3) within the 8-row segment, LDS slot i&7; global chunk
    // (i&7)^((i>>3)&7) so that stored slot == chunk ^ (row&7).
    const int grow = lane >> 3;                              // 0..7
    const int gcol = ((lane & 7) ^ grow) * 16;               // swizzled chunk
    const unsigned char* gA = reps + (size_t)(rowBase + wave * 8 + grow) * D_DIM + gcol;
    const unsigned char* gB = reps + (size_t)(colBase + wave * 8 + grow) * D_DIM + gcol;
    const int lbase = wave * 8 * BKB;                        // call j adds j*32*BKB
    unsigned char* lB = Bsmem + lbase;

    // fragment read offsets: m-frag row ra = wr*64 + m*16 + l15; lane reads
    // logical chunks {2*quad, 2*quad+1} (k = quad*32..+32) at slots
    // chunk^(ra&7) -> base off + (off^16).
    int aoff[4], boff[4];
    #pragma unroll
    for (int m = 0; m < 4; m++) {
        const int ra = wr * 64 + m * 16 + l15;
        const int rb = wc * 64 + m * 16 + l15;
        aoff[m] = ra * BKB + ((2 * quad) ^ (ra & 7)) * 16;
        boff[m] = rb * BKB + ((2 * quad) ^ (rb & 7)) * 16;
    }

    f32x4 acc[4][4];
    #pragma unroll
    for (int mi = 0; mi < 4; mi++)
        #pragma unroll
        for (int ni = 0; ni < 4; ni++)
            acc[mi][ni] = (f32x4){0.f, 0.f, 0.f, 0.f};

    // ---- prologue: stage A tile 0 -> buf 0, B tile 0; publish ----
    #pragma unroll
    for (int j = 0; j < 4; j++) {
        load_lds16(gA + j * 32 * D_DIM, &Asmem[0][lbase + j * 32 * BKB]);
        load_lds16(gB + j * 32 * D_DIM, lB + j * 32 * BKB);
    }
    __syncthreads();   // vmcnt(0) drain: tile 0 published

    for (int it = 0; it < KITERS; ++it) {   // 8 iters
        const int cur = it & 1;
        const unsigned char* pA = Asmem[cur];
        const bool pf = (it + 1 < KITERS);
        const int kn = (it + 1) * BKB;

        // issue next A staging FIRST into the idle buffer (safe: its reads
        // finished before the previous iter's end barrier). ~250cy earlier
        // than R19 -> fully covered by ds_read + barrier + MFMA below.
        if (pf) {
            unsigned char* sA = &Asmem[cur ^ 1][lbase];
            #pragma unroll
            for (int j = 0; j < 4; j++)
                load_lds16(gA + kn + j * 32 * D_DIM, sA + j * 32 * BKB);
        }

        // read this tile's fragments into regs
        i32x8 af[4], bf[4];
        #pragma unroll
        for (int m = 0; m < 4; m++) {
            const int4 alo = *(const int4*)(pA + aoff[m]);
            const int4 ahi = *(const int4*)(pA + (aoff[m] ^ 16));
            af[m] = (i32x8){alo.x, alo.y, alo.z, alo.w, ahi.x, ahi.y, ahi.z, ahi.w};
            const int4 blo = *(const int4*)(Bsmem + boff[m]);
            const int4 bhi = *(const int4*)(Bsmem + (boff[m] ^ 16));
            bf[m] = (i32x8){blo.x, blo.y, blo.z, blo.w, bhi.x, bhi.y, bhi.z, bhi.w};
        }
        __syncthreads();   // all waves done reading B -> B overwrite safe

        // stage next B tile before the MFMAs (DMA flies under them, as R19)
        if (pf) {
            #pragma unroll
            for (int j = 0; j < 4; j++)
                load_lds16(gB + kn + j * 32 * D_DIM, lB + j * 32 * BKB);
        }

        #pragma unroll
        for (int mi = 0; mi < 4; mi++)
            #pragma unroll
            for (int ni = 0; ni < 4; ni++)
                acc[mi][ni] = __builtin_amdgcn_mfma_scale_f32_16x16x128_f8f6f4(
                    af[mi], bf[ni], acc[mi][ni],
                    0, 0,          // cbsz=0 (fp8 e4m3 A), blgp=0 (fp8 e4m3 B)
                    0, 127,        // scale A: opsel 0, e8m0 127 = 1.0
                    0, 127);       // scale B: unit

        // publish barrier: vmcnt(0) drain overlapped with the MFMAs above
        if (pf) __syncthreads();
    }

    // Epilogue. C layout: col = lane&15, row = quad*4 + reg (shape-determined).
    // sim computed on 16x-scaled fp8 -> exp factor 2/256.
    float csum[4] = {0.f, 0.f, 0.f, 0.f};
    #pragma unroll
    for (int mi = 0; mi < 4; mi++) {
        const int rowA = rowBase + wr * 64 + mi * 16 + quad * 4;
        float prow[4] = {0.f, 0.f, 0.f, 0.f};
        #pragma unroll
        for (int ni = 0; ni < 4; ni++) {
            const int col = colBase + wc * 64 + ni * 16 + l15;
            const f32x4 a = acc[mi][ni];
            #pragma unroll
            for (int r = 0; r < 4; r++) {
                float e = __expf(a[r] * EXP_SCALE);
                if (isDiag && rowA + r == col) e = 0.0f;   // self-sim mask
                csum[ni] += e;
                prow[r]  += e;
            }
        }
        if (!isDiag) {
            #pragma unroll
            for (int r = 0; r < 4; r++) {   // row sums -> mirror tile
                float v = prow[r];
                v += __shfl_xor(v, 1);
                v += __shfl_xor(v, 2);
                v += __shfl_xor(v, 4);
                v += __shfl_xor(v, 8);
                if (l15 == 0) atomicAdd(denom + rowA + r, v);
            }
        }
    }
    #pragma unroll
    for (int ni = 0; ni < 4; ni++) {        // column sums across 4 quads
        float v = csum[ni];
        v += __shfl_xor(v, 16);
        v += __shfl_xor(v, 32);
        if (quad == 0)
            atomicAdd(denom + colBase + wc * 64 + ni * 16 + l15, v);
    }
}

// ---------------------------------------------------------------------------
// Kernel 3: loss = mean over 2B rows of (log(denom) - pos/T). Single block,
// 1024 threads (8 loop iters).
// ---------------------------------------------------------------------------
__global__ __launch_bounds__(1024)
void loss_kernel(const float* __restrict__ denom,
                 const float* __restrict__ pos,
                 float* __restrict__ out) {
    const int t = threadIdx.x;
    float s = 0.f;
    for (int i = t; i < N_ROWS; i += 1024) {
        const float p = pos[i & (B_ROWS - 1)];
        s += logf(denom[i]) - p * 2.0f;     // TEMP_INV, pos is unscaled fp32
    }
    #pragma unroll
    for (int off = 32; off >= 1; off >>= 1) s += __shfl_xor(s, off);
    __shared__ float red[16];
    if ((t & 63) == 0) red[t >> 6] = s;
    __syncthreads();
    if (t == 0) {
        float tot = 0.f;
        #pragma unroll
        for (int w = 0; w < 16; w++) tot += red[w];
        out[0] = tot / (float)N_ROWS;
    }
}

// ---------------------------------------------------------------------------
extern "C" void kernel_launch(void* const* d_in, const int* in_sizes, int n_in,
                              void* d_out, int out_size, void* d_ws, size_t ws_size,
                              hipStream_t stream) {
    const float* emb_i = (const float*)d_in[0];
    const float* emb_j = (const float*)d_in[1];

    unsigned char* reps = (unsigned char*)d_ws;                       // 8 MB fp8 [8192][1024]
    float* pos   = (float*)((char*)d_ws + (size_t)N_ROWS * D_DIM);    // 16 KB
    float* denom = pos + B_ROWS;                                      // 32 KB
    float* out   = (float*)d_out;

    normalize_kernel<<<B_ROWS, 256, 0, stream>>>(emb_i, emb_j, reps, pos, denom);
    sim_denom_kernel<<<GRID_SIM, 256, 0, stream>>>(reps, denom);
    loss_kernel<<<1, 1024, 0, stream>>>(denom, pos, out);
}

// Round 14
// 125.366 us; speedup vs baseline: 1.3264x; 1.0553x over previous
//
#include <hip/hip_runtime.h>
#include <hip/hip_bf16.h>

// Problem constants (B=4096, D=1024 per reference setup_inputs)
#define B_ROWS 4096
#define D_DIM  1024          // elements == bytes in fp8
#define N_ROWS 8192          // 2B
// values scaled by 16 before fp8 cast -> sim scaled by 256; exp arg factor:
#define EXP_SCALE 0.0078125f // TEMP_INV / 256 = 2/256
#define FP8_SCALE 16.0f

#define NTILE 64
#define GRID_SIM 2080        // upper-triangle tiles incl. diagonal (8 x 260)

typedef __attribute__((ext_vector_type(4))) float f32x4;   // MFMA C/D frag
typedef __attribute__((ext_vector_type(8))) int   i32x8;   // MX MFMA A/B frag

// Async global->LDS DMA, 16 B per lane. LDS dest is WAVE-UNIFORM base;
// lane i's 16 B land at base + i*16 (per-lane global addr is free-form).
__device__ inline void load_lds16(const unsigned char* g, unsigned char* l) {
    __builtin_amdgcn_global_load_lds(
        (const __attribute__((address_space(1))) unsigned int*)g,
        (__attribute__((address_space(3))) unsigned int*)l,
        16, 0, 0);
}

// ---------------------------------------------------------------------------
// Kernel 1 (R13 form, proven): block-per-row L2 normalize -> fp8 e4m3 reps
// (x16 scale), [8192] rows x 1024 B. 4096 blocks x 256 thr; thread t owns
// elements 4t..4t+3 of row b in BOTH emb_i and emb_j. Coalesced 16 B/lane
// loads, butterfly + LDS cross-wave reduce, 4 B/lane fp8 stores.
// pos[b] = z_i(b).z_j(b) in fp32 (exact). Zeroes denom (blocks 0..31).
// ---------------------------------------------------------------------------
__global__ __launch_bounds__(256)
void normalize_kernel(const float* __restrict__ emb_i,
                      const float* __restrict__ emb_j,
                      unsigned char* __restrict__ reps,
                      float* __restrict__ pos,
                      float* __restrict__ denom) {
    const int b    = blockIdx.x;                     // 0..4095 (one row pair)
    const int t    = threadIdx.x;                    // 0..255
    const int lane = t & 63;
    const int wave = t >> 6;

    if (b < N_ROWS / 256) denom[b * 256 + t] = 0.0f;

    const float4 vi = ((const float4*)(emb_i + (size_t)b * D_DIM))[t];
    const float4 vj = ((const float4*)(emb_j + (size_t)b * D_DIM))[t];

    float si = vi.x*vi.x + vi.y*vi.y + vi.z*vi.z + vi.w*vi.w;
    float sj = vj.x*vj.x + vj.y*vj.y + vj.z*vj.z + vj.w*vj.w;
    float sd = vi.x*vj.x + vi.y*vj.y + vi.z*vj.z + vi.w*vj.w;

    #pragma unroll
    for (int off = 32; off >= 1; off >>= 1) {   // butterfly within wave
        si += __shfl_xor(si, off);
        sj += __shfl_xor(sj, off);
        sd += __shfl_xor(sd, off);
    }
    __shared__ float red[3][4];
    if (lane == 0) { red[0][wave] = si; red[1][wave] = sj; red[2][wave] = sd; }
    __syncthreads();
    si = red[0][0] + red[0][1] + red[0][2] + red[0][3];
    sj = red[1][0] + red[1][1] + red[1][2] + red[1][3];
    sd = red[2][0] + red[2][1] + red[2][2] + red[2][3];

    const float inv_i = FP8_SCALE / fmaxf(sqrtf(si), 1e-12f);
    const float inv_j = FP8_SCALE / fmaxf(sqrtf(sj), 1e-12f);
    if (t == 0) pos[b] = sd * (inv_i * inv_j) * (1.0f / (FP8_SCALE * FP8_SCALE));

    int a  = __builtin_amdgcn_cvt_pk_fp8_f32(vi.x * inv_i, vi.y * inv_i, 0, false);
    unsigned int ui = __builtin_amdgcn_cvt_pk_fp8_f32(vi.z * inv_i, vi.w * inv_i, a, true);
    int c  = __builtin_amdgcn_cvt_pk_fp8_f32(vj.x * inv_j, vj.y * inv_j, 0, false);
    unsigned int uj = __builtin_amdgcn_cvt_pk_fp8_f32(vj.z * inv_j, vj.w * inv_j, c, true);

    ((unsigned int*)(reps + (size_t)b * D_DIM))[t]            = ui;
    ((unsigned int*)(reps + (size_t)(b + B_ROWS) * D_DIM))[t] = uj;
}

// ---------------------------------------------------------------------------
// Kernel 2 (R22 = exact R19, the session-best sim at 53 us):
// 128x128 upper-triangle tile, MX-fp8 MFMA, XCD swizzle + stage-under-MFMA.
//
// Order: read frags(t) -> barrier[LDS dead] -> stage(t+1) -> MFMA(t)
//        -> barrier[vmcnt0 drain overlapped by MFMAs].
// This placement is OPTIMAL for a __syncthreads loop: __syncthreads always
// compiler-drains vmcnt(0), so DMA issue must sit immediately after a
// barrier with a full MFMA block before the next one.
//
// RETIRED LEVERS (all bench-verified regressions — do not retry):
//  - deeper pipelines / full LDS dbuf (R9-R12: occupancy loss or barrier
//    overhead; at K=1024 there are only 8 K-iters to amortize)
//  - occupancy 4 blocks/CU (R14: 128-reg cap spills acc, WRITE 152 MB)
//  - loss fusion, fence or fence-free (R15: threadfence L2 poison 57->236;
//    R17: ticket tail alone 57->72)
//  - B operands direct from global (R20: serial L2 latency, 53->94)
//  - A-only dbuf with early issue (R21: mid-barrier vmcnt drain exposed,
//    53->57.5; WRITE 13->29 MB)
//
// LDS: 128-B rows; 16-B chunk c of row r at slot c ^ (r&7). Fragment
// reads: per frag two ds_read_b128 at off, off^16. A and B use the same
// lane->k map, so the k-permutation cancels in the dot product; C/D layout
// is shape-determined (col=lane&15, row=quad*4+reg).
// ---------------------------------------------------------------------------
#define BM 128
#define BKB 128              // K-bytes (== elements) staged per iter

__global__ __launch_bounds__(256, 3)
void sim_denom_kernel(const unsigned char* __restrict__ reps,
                      float* __restrict__ denom) {
    // ---- XCD-aware swizzle: physical bid -> logical tile id (R18) ----
    const int bid = (blockIdx.x & 7) * (GRID_SIM / 8) + (blockIdx.x >> 3);

    // ---- tile decode: bid -> (rt, ct), rt <= ct (grouped enumeration) ----
    int g = (int)((__builtin_sqrtf(1.0f + 8.0f * (float)bid) - 1.0f) * 0.125f);
    while (8 * (g + 1) * (g + 1) + 2 * (g + 1) <= bid) g++;
    while (8 * g * g + 2 * g > bid) g--;
    const int i = bid - (8 * g * g + 2 * g);    // [0, 16g+10)
    int rt, c;
    if (i < 16 * g + 4) { rt = i >> 2; c = i & 3; }
    else {
        const int r2 = i - (16 * g + 4);        // 0..5
        const int ra[6] = {1, 1, 1, 2, 2, 3};
        const int ca[6] = {1, 2, 3, 2, 3, 3};
        rt = 4 * g + ra[r2]; c = ca[r2];
    }
    const int ct = 4 * g + c;
    const bool isDiag = (rt == ct);
    const int rowBase = rt * BM;
    const int colBase = ct * BM;

    const int t    = threadIdx.x;
    const int lane = t & 63;
    const int wave = t >> 6;
    const int wr   = wave >> 1;           // wave row quadrant (0/1)
    const int wc   = wave & 1;            // wave col quadrant (0/1)
    const int quad = lane >> 4;           // 0..3
    const int l15  = lane & 15;

    __shared__ __align__(16) unsigned char Asmem[BM * BKB];   // 16 KB
    __shared__ __align__(16) unsigned char Bsmem[BM * BKB];   // 16 KB

    // staging lane map: per call a wave stages 8 rows (1 KB). lane i ->
    // row (i>>3) within the 8-row segment, LDS slot i&7; global chunk
    // (i&7)^((i>>3)&7) so that stored slot == chunk ^ (row&7).
    const int grow = lane >> 3;                              // 0..7
    const int gcol = ((lane & 7) ^ grow) * 16;               // swizzled chunk
    const unsigned char* gA = reps + (size_t)(rowBase + wave * 8 + grow) * D_DIM + gcol;
    const unsigned char* gB = reps + (size_t)(colBase + wave * 8 + grow) * D_DIM + gcol;
    unsigned char* lA = Asmem + wave * 8 * BKB;              // call j adds j*32*BKB
    unsigned char* lB = Bsmem + wave * 8 * BKB;

    // fragment read offsets: m-frag row ra = wr*64 + m*16 + l15; lane reads
    // logical chunks {2*quad, 2*quad+1} (k = quad*32..+32) at slots
    // chunk^(ra&7) -> base off + (off^16).
    int aoff[4], boff[4];
    #pragma unroll
    for (int m = 0; m < 4; m++) {
        const int ra = wr * 64 + m * 16 + l15;
        const int rb = wc * 64 + m * 16 + l15;
        aoff[m] = ra * BKB + ((2 * quad) ^ (ra & 7)) * 16;
        boff[m] = rb * BKB + ((2 * quad) ^ (rb & 7)) * 16;
    }

    f32x4 acc[4][4];
    #pragma unroll
    for (int mi = 0; mi < 4; mi++)
        #pragma unroll
        for (int ni = 0; ni < 4; ni++)
            acc[mi][ni] = (f32x4){0.f, 0.f, 0.f, 0.f};

    // ---- prologue: stage tile 0, publish ----
    #pragma unroll
    for (int j = 0; j < 4; j++) {
        load_lds16(gA + j * 32 * D_DIM, lA + j * 32 * BKB);
        load_lds16(gB + j * 32 * D_DIM, lB + j * 32 * BKB);
    }
    __syncthreads();   // vmcnt(0) drain: tile 0 published

    for (int it = 0; it < D_DIM / BKB; ++it) {   // 8 iters
        const int kb = it * BKB;

        // read this tile's fragments into regs (LDS becomes dead after)
        i32x8 af[4], bf[4];
        #pragma unroll
        for (int m = 0; m < 4; m++) {
            const int4 alo = *(const int4*)(Asmem + aoff[m]);
            const int4 ahi = *(const int4*)(Asmem + (aoff[m] ^ 16));
            af[m] = (i32x8){alo.x, alo.y, alo.z, alo.w, ahi.x, ahi.y, ahi.z, ahi.w};
            const int4 blo = *(const int4*)(Bsmem + boff[m]);
            const int4 bhi = *(const int4*)(Bsmem + (boff[m] ^ 16));
            bf[m] = (i32x8){blo.x, blo.y, blo.z, blo.w, bhi.x, bhi.y, bhi.z, bhi.w};
        }
        __syncthreads();   // all waves done reading -> LDS overwrite safe

        // issue next tile's staging BEFORE the MFMAs (DMA flies under them)
        if (it < D_DIM / BKB - 1) {
            const int kn = kb + BKB;
            #pragma unroll
            for (int j = 0; j < 4; j++) {
                load_lds16(gA + kn + j * 32 * D_DIM, lA + j * 32 * BKB);
                load_lds16(gB + kn + j * 32 * D_DIM, lB + j * 32 * BKB);
            }
        }

        #pragma unroll
        for (int mi = 0; mi < 4; mi++)
            #pragma unroll
            for (int ni = 0; ni < 4; ni++)
                acc[mi][ni] = __builtin_amdgcn_mfma_scale_f32_16x16x128_f8f6f4(
                    af[mi], bf[ni], acc[mi][ni],
                    0, 0,          // cbsz=0 (fp8 e4m3 A), blgp=0 (fp8 e4m3 B)
                    0, 127,        // scale A: opsel 0, e8m0 127 = 1.0
                    0, 127);       // scale B: unit

        // publish barrier: vmcnt(0) drain now overlapped with the MFMAs above
        if (it < D_DIM / BKB - 1) __syncthreads();
    }

    // Epilogue. C layout: col = lane&15, row = quad*4 + reg (shape-determined).
    // sim computed on 16x-scaled fp8 -> exp factor 2/256.
    float csum[4] = {0.f, 0.f, 0.f, 0.f};
    #pragma unroll
    for (int mi = 0; mi < 4; mi++) {
        const int rowA = rowBase + wr * 64 + mi * 16 + quad * 4;
        float prow[4] = {0.f, 0.f, 0.f, 0.f};
        #pragma unroll
        for (int ni = 0; ni < 4; ni++) {
            const int col = colBase + wc * 64 + ni * 16 + l15;
            const f32x4 a = acc[mi][ni];
            #pragma unroll
            for (int r = 0; r < 4; r++) {
                float e = __expf(a[r] * EXP_SCALE);
                if (isDiag && rowA + r == col) e = 0.0f;   // self-sim mask
                csum[ni] += e;
                prow[r]  += e;
            }
        }
        if (!isDiag) {
            #pragma unroll
            for (int r = 0; r < 4; r++) {   // row sums -> mirror tile
                float v = prow[r];
                v += __shfl_xor(v, 1);
                v += __shfl_xor(v, 2);
                v += __shfl_xor(v, 4);
                v += __shfl_xor(v, 8);
                if (l15 == 0) atomicAdd(denom + rowA + r, v);
            }
        }
    }
    #pragma unroll
    for (int ni = 0; ni < 4; ni++) {        // column sums across 4 quads
        float v = csum[ni];
        v += __shfl_xor(v, 16);
        v += __shfl_xor(v, 32);
        if (quad == 0)
            atomicAdd(denom + colBase + wc * 64 + ni * 16 + l15, v);
    }
}

// ---------------------------------------------------------------------------
// Kernel 3: loss = mean over 2B rows of (log(denom) - pos/T). Single block,
// 1024 threads (8 loop iters).
// ---------------------------------------------------------------------------
__global__ __launch_bounds__(1024)
void loss_kernel(const float* __restrict__ denom,
                 const float* __restrict__ pos,
                 float* __restrict__ out) {
    const int t = threadIdx.x;
    float s = 0.f;
    for (int i = t; i < N_ROWS; i += 1024) {
        const float p = pos[i & (B_ROWS - 1)];
        s += logf(denom[i]) - p * 2.0f;     // TEMP_INV, pos is unscaled fp32
    }
    #pragma unroll
    for (int off = 32; off >= 1; off >>= 1) s += __shfl_xor(s, off);
    __shared__ float red[16];
    if ((t & 63) == 0) red[t >> 6] = s;
    __syncthreads();
    if (t == 0) {
        float tot = 0.f;
        #pragma unroll
        for (int w = 0; w < 16; w++) tot += red[w];
        out[0] = tot / (float)N_ROWS;
    }
}

// ---------------------------------------------------------------------------
extern "C" void kernel_launch(void* const* d_in, const int* in_sizes, int n_in,
                              void* d_out, int out_size, void* d_ws, size_t ws_size,
                              hipStream_t stream) {
    const float* emb_i = (const float*)d_in[0];
    const float* emb_j = (const float*)d_in[1];

    unsigned char* reps = (unsigned char*)d_ws;                       // 8 MB fp8 [8192][1024]
    float* pos   = (float*)((char*)d_ws + (size_t)N_ROWS * D_DIM);    // 16 KB
    float* denom = pos + B_ROWS;                                      // 32 KB
    float* out   = (float*)d_out;

    normalize_kernel<<<B_ROWS, 256, 0, stream>>>(emb_i, emb_j, reps, pos, denom);
    sim_denom_kernel<<<GRID_SIM, 256, 0, stream>>>(reps, denom);
    loss_kernel<<<1, 1024, 0, stream>>>(denom, pos, out);
}